// Round 3
// baseline (255.873 us; speedup 1.0000x reference)
//
#include <hip/hip_runtime.h>
#include <hip/hip_bf16.h>

// NNUE fused: C = clip(stacked_emb @ acc_w^T + acc_b, 0, 6); out[b] = sum_d C * out_w[sel[b]] + out_b[sel[b]]
// M = 32768 (stm rows 0..16383, nstm rows 16384..32767), K = 768, N = 1024.
// Grid: 256 (mb) x 8 (nb) = 2048 blocks, 256 thr (4 waves), tile 128x128, BK=64.
// Wave (wr,wc) owns a 64x64 subtile as 4x4 MFMA 16x16x32 bf16 fragments.

#define INPUTSZ 768
#define ACCSZ   1024
#define NROWS   16384

typedef __bf16 bf16x8  __attribute__((ext_vector_type(8)));
typedef __bf16 bf16x4v __attribute__((ext_vector_type(4)));
typedef float  f32x4   __attribute__((ext_vector_type(4)));

__global__ void init_out(const int* __restrict__ sel, const float* __restrict__ out_b,
                         float* __restrict__ out) {
    int i = blockIdx.x * 256 + threadIdx.x;
    out[i] = out_b[sel[i]];
}

__global__ __launch_bounds__(256, 2) void nnue_fused(
    const float* __restrict__ stm, const float* __restrict__ nstm,
    const int* __restrict__ sel, const float* __restrict__ acc_w,
    const float* __restrict__ acc_b, const float* __restrict__ out_w,
    float* __restrict__ out)
{
    // 64 KiB LDS total -> 2 blocks/CU
    __shared__ alignas(16) __bf16 As[2][128 * 64];
    __shared__ alignas(16) __bf16 Bs[2][128 * 64];

    const int tid  = threadIdx.x;
    const int flat = blockIdx.x;
    const int nb   = flat & 7;    // N-tile index (0..7)
    const int mb   = flat >> 3;   // M-tile index (0..255)

    const int lane = tid & 63;
    const int w    = tid >> 6;
    const int wr   = w >> 1, wc = w & 1;
    const int l15  = lane & 15, l4 = lane >> 4;

    // A source: rows mb*128..+128 of virtual stacked matrix (128 | 16384, so no straddle)
    const float* Aptr = (mb < 128) ? stm : nstm;
    const float4* Asrc = (const float4*)Aptr + (size_t)(mb & 127) * 128 * (INPUTSZ / 4);
    const float4* Bsrc = (const float4*)acc_w + (size_t)nb * 128 * (INPUTSZ / 4);

    float4 ra[8], rb[8];
    // prologue: load K-tile 0 into regs
#pragma unroll
    for (int p = 0; p < 8; ++p) {
        int i = tid + p * 256;
        int r = i >> 4, c = i & 15;            // row 0..127, float4-chunk 0..15
        ra[p] = Asrc[r * (INPUTSZ / 4) + c];
        rb[p] = Bsrc[r * (INPUTSZ / 4) + c];
    }

    f32x4 acc[4][4];
#pragma unroll
    for (int mt = 0; mt < 4; ++mt)
#pragma unroll
        for (int nt = 0; nt < 4; ++nt) {
            f32x4 z = {0.f, 0.f, 0.f, 0.f};
            acc[mt][nt] = z;
        }

    int buf = 0;
    for (int kb = 0; kb < 12; ++kb) {
        // convert + store staged regs (tile kb) into LDS buf, XOR-swizzled (G4 recipe)
#pragma unroll
        for (int p = 0; p < 8; ++p) {
            int i = tid + p * 256;
            int r = i >> 4, c = i & 15;
            int ke = (c * 4) ^ ((r & 7) << 3);  // element offset within 64-wide row
            bf16x4v va; va[0] = (__bf16)ra[p].x; va[1] = (__bf16)ra[p].y;
                        va[2] = (__bf16)ra[p].z; va[3] = (__bf16)ra[p].w;
            *(bf16x4v*)&As[buf][r * 64 + ke] = va;
            bf16x4v vb; vb[0] = (__bf16)rb[p].x; vb[1] = (__bf16)rb[p].y;
                        vb[2] = (__bf16)rb[p].z; vb[3] = (__bf16)rb[p].w;
            *(bf16x4v*)&Bs[buf][r * 64 + ke] = vb;
        }
        // issue next tile's global loads (latency hides under barrier + MFMA)
        if (kb < 11) {
#pragma unroll
            for (int p = 0; p < 8; ++p) {
                int i = tid + p * 256;
                int r = i >> 4, c = i & 15;
                ra[p] = Asrc[r * (INPUTSZ / 4) + (kb + 1) * 16 + c];
                rb[p] = Bsrc[r * (INPUTSZ / 4) + (kb + 1) * 16 + c];
            }
        }
        __syncthreads();   // single barrier per iter: buf ready; prev reads of buf^1 done

        // compute on buf: 2 K-steps of 32, 4x4 fragment tiles
#pragma unroll
        for (int kt = 0; kt < 2; ++kt) {
            bf16x8 af[4], bfr[4];
#pragma unroll
            for (int mt = 0; mt < 4; ++mt) {
                int arow = wr * 64 + mt * 16 + l15;
                int ke = (kt * 32 + l4 * 8) ^ ((arow & 7) << 3);
                af[mt] = *(const bf16x8*)&As[buf][arow * 64 + ke];
            }
#pragma unroll
            for (int nt = 0; nt < 4; ++nt) {
                int brow = wc * 64 + nt * 16 + l15;
                int ke = (kt * 32 + l4 * 8) ^ ((brow & 7) << 3);
                bfr[nt] = *(const bf16x8*)&Bs[buf][brow * 64 + ke];
            }
#pragma unroll
            for (int mt = 0; mt < 4; ++mt)
#pragma unroll
                for (int nt = 0; nt < 4; ++nt)
                    acc[mt][nt] = __builtin_amdgcn_mfma_f32_16x16x32_bf16(
                        af[mt], bfr[nt], acc[mt][nt], 0, 0, 0);
        }
        buf ^= 1;
    }

    // ---- fused epilogue: bias, clip, layer-2 dot, reduce, atomic accumulate ----
    float biasv[4];
#pragma unroll
    for (int nt = 0; nt < 4; ++nt)
        biasv[nt] = acc_b[nb * 128 + wc * 64 + nt * 16 + l15];

#pragma unroll
    for (int mt = 0; mt < 4; ++mt) {
#pragma unroll
        for (int r = 0; r < 4; ++r) {
            int row_local = wr * 64 + mt * 16 + l4 * 4 + r;   // C/D: row = 4*(lane>>4)+reg
            int grow = mb * 128 + row_local;
            int half = grow >> 14;            // 0 = stm, 1 = nstm
            int b    = grow & (NROWS - 1);
            int s    = sel[b];
            const float* w2r = out_w + (size_t)s * (2 * ACCSZ) + half * ACCSZ
                               + nb * 128 + wc * 64;
            float ps = 0.f;
#pragma unroll
            for (int nt = 0; nt < 4; ++nt) {
                float v = acc[mt][nt][r] + biasv[nt];
                v = fminf(fmaxf(v, 0.f), 6.f);
                ps += v * w2r[nt * 16 + l15];
            }
            // reduce across the 16 column-lanes (same l4 group)
            ps += __shfl_xor(ps, 1, 64);
            ps += __shfl_xor(ps, 2, 64);
            ps += __shfl_xor(ps, 4, 64);
            ps += __shfl_xor(ps, 8, 64);
            if (l15 == 0)
                atomicAdd(&out[b], ps);
        }
    }
}

extern "C" void kernel_launch(void* const* d_in, const int* in_sizes, int n_in,
                              void* d_out, int out_size, void* d_ws, size_t ws_size,
                              hipStream_t stream) {
    const float* stm  = (const float*)d_in[0];
    const float* nstm = (const float*)d_in[1];
    const int*   sel  = (const int*)d_in[2];
    const float* accw = (const float*)d_in[3];
    const float* accb = (const float*)d_in[4];
    const float* outw = (const float*)d_in[5];
    const float* outb = (const float*)d_in[6];
    float* out = (float*)d_out;

    // d_out is re-poisoned before every launch: seed with out_b[sel[b]]
    init_out<<<NROWS / 256, 256, 0, stream>>>(sel, outb, out);
    nnue_fused<<<2048, 256, 0, stream>>>(stm, nstm, sel, accw, accb, outw, out);
}